// Round 3
// baseline (28.892 us; speedup 1.0000x reference)
//
#include <hip/hip_runtime.h>

#define NQ 8
#define NL 4
#define NO 16  // = 2*NQ output features

typedef __attribute__((ext_vector_type(4))) float float4v;

__global__ __launch_bounds__(256) void qcl_fused(
    const float* __restrict__ x,    // [B,S,64] f32
    const float* __restrict__ rot,  // [NL,NQ,3] f32
    const float* __restrict__ ent,  // [NL,NQ-1] f32
    const float* __restrict__ pw,   // [NO,NQ] f32
    const float* __restrict__ pb,   // [NO] f32
    float* __restrict__ out,        // [B,S,NO] f32
    int n_rows)
{
    __shared__ float sW[NO][NQ];
    __shared__ float sB[NO];
    const int tid = threadIdx.x;

    // ---- prologue: threads 0..15 compose W_eff = proj_w * prod_l (E_l D_l) ----
    if (tid < NO) {
        float W[NQ];
        #pragma unroll
        for (int q = 0; q < NQ; ++q) W[q] = pw[tid * NQ + q];

        #pragma unroll
        for (int l = NL - 1; l >= 0; --l) {
            // sigmoid(entangle_params[l])
            float wl[NQ - 1];
            #pragma unroll
            for (int i = 0; i < NQ - 1; ++i) {
                float e = __expf(-ent[l * (NQ - 1) + i]);
                wl[i] = __builtin_amdgcn_rcpf(1.0f + e);
            }
            // W <- W * E_l   (E: [i][i]=1-w_i, [i][i+1]=w_i for i<7; [7][7]=1)
            float WE[NQ];
            WE[0] = W[0] * (1.0f - wl[0]);
            #pragma unroll
            for (int j = 1; j < NQ - 1; ++j)
                WE[j] = W[j] * (1.0f - wl[j]) + W[j - 1] * wl[j - 1];
            WE[NQ - 1] = W[NQ - 1] + W[NQ - 2] * wl[NQ - 2];
            // W <- (W E_l) * D_l,  D = diag((cos+sin)(r0)*(cos+sin)(r1)*(cos+sin)(r2))
            #pragma unroll
            for (int q = 0; q < NQ; ++q) {
                float r0 = rot[(l * NQ + q) * 3 + 0];
                float r1 = rot[(l * NQ + q) * 3 + 1];
                float r2 = rot[(l * NQ + q) * 3 + 2];
                float s = (__cosf(r0) + __sinf(r0)) *
                          (__cosf(r1) + __sinf(r1)) *
                          (__cosf(r2) + __sinf(r2));
                W[q] = WE[q] * s;
            }
        }
        #pragma unroll
        for (int q = 0; q < NQ; ++q) sW[tid][q] = W[q];
        sB[tid] = pb[tid];
    }
    __syncthreads();

    // ---- main: one thread per (b,s) row ----
    const int r = blockIdx.x * 256 + tid;
    if (r >= n_rows) return;

    // first 8 f32 of the 64-feature row: two 16B loads
    const float4v* xp = (const float4v*)(x + (size_t)r * 64);
    float4v x0 = xp[0];
    float4v x1 = xp[1];
    float xs[NQ] = {x0.x, x0.y, x0.z, x0.w, x1.x, x1.y, x1.z, x1.w};

    float t[NQ];
    #pragma unroll
    for (int q = 0; q < NQ; ++q) {
        // tanh(v) = 1 - 2/(e^{2v}+1); saturates correctly for large |v|
        float e = __expf(2.0f * xs[q]);
        t[q] = 1.0f - 2.0f * __builtin_amdgcn_rcpf(e + 1.0f);
    }

    float acc[NO];
    #pragma unroll
    for (int o = 0; o < NO; ++o) {
        float a = sB[o];
        #pragma unroll
        for (int q = 0; q < NQ; ++q) a += sW[o][q] * t[q];
        acc[o] = a;
    }

    float4v* ov = (float4v*)(out + (size_t)r * NO);
    #pragma unroll
    for (int i = 0; i < 4; ++i) {
        float4v v;
        v.x = acc[4 * i + 0];
        v.y = acc[4 * i + 1];
        v.z = acc[4 * i + 2];
        v.w = acc[4 * i + 3];
        ov[i] = v;
    }
}

extern "C" void kernel_launch(void* const* d_in, const int* in_sizes, int n_in,
                              void* d_out, int out_size, void* d_ws, size_t ws_size,
                              hipStream_t stream) {
    const float* x   = (const float*)d_in[0];
    const float* rot = (const float*)d_in[1];
    const float* ent = (const float*)d_in[2];
    const float* pw  = (const float*)d_in[3];
    const float* pb  = (const float*)d_in[4];
    float* out = (float*)d_out;

    const int n_rows = in_sizes[0] / 64;           // B*S = 524288
    const int block = 256;
    const int grid = (n_rows + block - 1) / block; // 2048
    hipLaunchKernelGGL(qcl_fused, dim3(grid), dim3(block), 0, stream,
                       x, rot, ent, pw, pb, out, n_rows);
}

// Round 4
// 27.346 us; speedup vs baseline: 1.0565x; 1.0565x over previous
//
#include <hip/hip_runtime.h>

#define NQ 8
#define NL 4
#define NO 16  // = 2*NQ output features

typedef __attribute__((ext_vector_type(4))) float float4v;

__global__ __launch_bounds__(256) void qcl_fused(
    const float* __restrict__ x,    // [B,S,64] f32
    const float* __restrict__ rot,  // [NL,NQ,3] f32
    const float* __restrict__ ent,  // [NL,NQ-1] f32
    const float* __restrict__ pw,   // [NO,NQ] f32
    const float* __restrict__ pb,   // [NO] f32
    float* __restrict__ out,        // [B,S,NO] f32
    int n_rows)
{
    __shared__ float sW[NO][NQ];
    __shared__ float sB[NO];
    const int tid = threadIdx.x;

    // ---- prologue: threads 0..15 compose W_eff = proj_w * prod_l (E_l D_l) ----
    if (tid < NO) {
        float W[NQ];
        #pragma unroll
        for (int q = 0; q < NQ; ++q) W[q] = pw[tid * NQ + q];

        #pragma unroll
        for (int l = NL - 1; l >= 0; --l) {
            float wl[NQ - 1];
            #pragma unroll
            for (int i = 0; i < NQ - 1; ++i) {
                float e = __expf(-ent[l * (NQ - 1) + i]);
                wl[i] = __builtin_amdgcn_rcpf(1.0f + e);
            }
            float WE[NQ];
            WE[0] = W[0] * (1.0f - wl[0]);
            #pragma unroll
            for (int j = 1; j < NQ - 1; ++j)
                WE[j] = W[j] * (1.0f - wl[j]) + W[j - 1] * wl[j - 1];
            WE[NQ - 1] = W[NQ - 1] + W[NQ - 2] * wl[NQ - 2];
            #pragma unroll
            for (int q = 0; q < NQ; ++q) {
                float r0 = rot[(l * NQ + q) * 3 + 0];
                float r1 = rot[(l * NQ + q) * 3 + 1];
                float r2 = rot[(l * NQ + q) * 3 + 2];
                float s = (__cosf(r0) + __sinf(r0)) *
                          (__cosf(r1) + __sinf(r1)) *
                          (__cosf(r2) + __sinf(r2));
                W[q] = WE[q] * s;
            }
        }
        #pragma unroll
        for (int q = 0; q < NQ; ++q) sW[tid][q] = W[q];
        sB[tid] = pb[tid];
    }
    __syncthreads();

    // ---- main: 2 lanes per row (pair-split), 2 half-rows per thread ----
    // half-row g: row = g>>1, half h = g&1 (lane-parity). Lane loads its 16B
    // half of the row prefix; pair exchanges tanh results via shfl_xor(1).
    const int nhalf = n_rows * 2;
    const int H = gridDim.x * 256;          // threads launched
    const int gid = blockIdx.x * 256 + tid;
    const int h = tid & 1;                   // same parity for g0 and g1

    const int g0 = gid;
    const int g1 = gid + H;
    const bool v0 = g0 < nhalf;
    const bool v1 = g1 < nhalf;

    float4v a0 = {0.f, 0.f, 0.f, 0.f};
    float4v a1 = {0.f, 0.f, 0.f, 0.f};
    if (v0) a0 = *(const float4v*)(x + (size_t)(g0 >> 1) * 64 + h * 4);
    if (v1) a1 = *(const float4v*)(x + (size_t)(g1 >> 1) * 64 + h * 4);

    // tanh of my 4 values for each half-row
    float m0[4], m1[4];
    #pragma unroll
    for (int j = 0; j < 4; ++j) {
        float e0 = __expf(2.0f * a0[j]);
        m0[j] = 1.0f - 2.0f * __builtin_amdgcn_rcpf(e0 + 1.0f);
        float e1 = __expf(2.0f * a1[j]);
        m1[j] = 1.0f - 2.0f * __builtin_amdgcn_rcpf(e1 + 1.0f);
    }

    // exchange with pair lane (both lanes of a pair are uniformly active)
    float tA[8], tB[8];
    #pragma unroll
    for (int j = 0; j < 4; ++j) {
        float o0 = __shfl_xor(m0[j], 1, 64);
        float o1 = __shfl_xor(m1[j], 1, 64);
        tA[j]     = h ? o0 : m0[j];
        tA[j + 4] = h ? m0[j] : o0;
        tB[j]     = h ? o1 : m1[j];
        tB[j + 4] = h ? m1[j] : o1;
    }

    // each lane computes outputs [h*8, h*8+8); weight reads shared across rows
    const int base = h * 8;
    float accA[8], accB[8];
    #pragma unroll
    for (int j = 0; j < 8; ++j) {
        float aA = sB[base + j];
        float aB = aA;
        #pragma unroll
        for (int q = 0; q < NQ; ++q) {
            float w = sW[base + j][q];
            aA += w * tA[q];
            aB += w * tB[q];
        }
        accA[j] = aA;
        accB[j] = aB;
    }

    if (v0) {
        float4v* p = (float4v*)(out + (size_t)(g0 >> 1) * 16 + base);
        float4v u0 = {accA[0], accA[1], accA[2], accA[3]};
        float4v u1 = {accA[4], accA[5], accA[6], accA[7]};
        p[0] = u0; p[1] = u1;
    }
    if (v1) {
        float4v* p = (float4v*)(out + (size_t)(g1 >> 1) * 16 + base);
        float4v u0 = {accB[0], accB[1], accB[2], accB[3]};
        float4v u1 = {accB[4], accB[5], accB[6], accB[7]};
        p[0] = u0; p[1] = u1;
    }
}

extern "C" void kernel_launch(void* const* d_in, const int* in_sizes, int n_in,
                              void* d_out, int out_size, void* d_ws, size_t ws_size,
                              hipStream_t stream) {
    const float* x   = (const float*)d_in[0];
    const float* rot = (const float*)d_in[1];
    const float* ent = (const float*)d_in[2];
    const float* pw  = (const float*)d_in[3];
    const float* pb  = (const float*)d_in[4];
    float* out = (float*)d_out;

    const int n_rows = in_sizes[0] / 64;            // B*S = 524288
    const int nhalf = n_rows * 2;
    const int block = 256;
    // each thread covers 2 half-rows
    const int grid = (nhalf + block * 2 - 1) / (block * 2);  // 2048
    hipLaunchKernelGGL(qcl_fused, dim3(grid), dim3(block), 0, stream,
                       x, rot, ent, pw, pb, out, n_rows);
}

// Round 5
// 26.007 us; speedup vs baseline: 1.1109x; 1.0515x over previous
//
#include <hip/hip_runtime.h>

#define NQ 8
#define NL 4
#define NO 16  // = 2*NQ output features

typedef __attribute__((ext_vector_type(4))) float float4v;

__global__ __launch_bounds__(256) void qcl_fused(
    const float* __restrict__ x,    // [B,S,64] f32
    const float* __restrict__ rot,  // [NL,NQ,3] f32
    const float* __restrict__ ent,  // [NL,NQ-1] f32
    const float* __restrict__ pw,   // [NO,NQ] f32
    const float* __restrict__ pb,   // [NO] f32
    float* __restrict__ out,        // [B,S,NO] f32
    int n_rows)
{
    __shared__ float sScale[NL][NQ];     // (cos+sin)^3 per (layer,qubit)
    __shared__ float sWl[NL][NQ - 1];    // sigmoid(entangle)
    __shared__ float sW[NO][NQ];         // composed W_eff, row-major 32B rows
    __shared__ float sB[NO];

    const int tid = threadIdx.x;

    // ---- issue global loads FIRST: prologue overlaps their latency ----
    const int nhalf = n_rows * 2;
    const int H = gridDim.x * 256;
    const int gid = blockIdx.x * 256 + tid;
    const int h = tid & 1;
    const int g0 = gid;
    const int g1 = gid + H;
    const bool v0 = g0 < nhalf;
    const bool v1 = g1 < nhalf;

    float4v a0 = {0.f, 0.f, 0.f, 0.f};
    float4v a1 = {0.f, 0.f, 0.f, 0.f};
    if (v0) a0 = *(const float4v*)(x + (size_t)(g0 >> 1) * 64 + h * 4);
    if (v1) a1 = *(const float4v*)(x + (size_t)(g1 >> 1) * 64 + h * 4);

    // ---- distributed prologue: trans ops spread across 60 threads ----
    if (tid < NL * NQ) {                       // 32 threads: one scale each
        const int l = tid >> 3, q = tid & 7;
        const float r0 = rot[(l * NQ + q) * 3 + 0];
        const float r1 = rot[(l * NQ + q) * 3 + 1];
        const float r2 = rot[(l * NQ + q) * 3 + 2];
        sScale[l][q] = (__cosf(r0) + __sinf(r0)) *
                       (__cosf(r1) + __sinf(r1)) *
                       (__cosf(r2) + __sinf(r2));
    } else if (tid < NL * NQ + NL * (NQ - 1)) { // 28 threads: one sigmoid each
        const int u = tid - NL * NQ;
        const int l = u / 7, i = u - l * 7;
        const float e = __expf(-ent[l * 7 + i]);
        sWl[l][i] = __builtin_amdgcn_rcpf(1.0f + e);
    } else if (tid >= 64 && tid < 64 + NO) {    // 16 threads: bias
        sB[tid - 64] = pb[tid - 64];
    }
    __syncthreads();

    if (tid < NO) {   // FMA-only composition: W_eff = proj_w * prod_l (E_l D_l)
        float W[NQ];
        #pragma unroll
        for (int q = 0; q < NQ; ++q) W[q] = pw[tid * NQ + q];
        #pragma unroll
        for (int l = NL - 1; l >= 0; --l) {
            float WE[NQ];
            WE[0] = W[0] * (1.0f - sWl[l][0]);
            #pragma unroll
            for (int j = 1; j < NQ - 1; ++j)
                WE[j] = W[j] * (1.0f - sWl[l][j]) + W[j - 1] * sWl[l][j - 1];
            WE[NQ - 1] = W[NQ - 1] + W[NQ - 2] * sWl[l][NQ - 2];
            #pragma unroll
            for (int q = 0; q < NQ; ++q) W[q] = WE[q] * sScale[l][q];
        }
        #pragma unroll
        for (int q = 0; q < NQ; ++q) sW[tid][q] = W[q];
    }
    __syncthreads();

    if (!v0 && !v1) return;

    // ---- tanh of my 4 values per half-row ----
    float m0[4], m1[4];
    #pragma unroll
    for (int j = 0; j < 4; ++j) {
        float e0 = __expf(2.0f * a0[j]);
        m0[j] = 1.0f - 2.0f * __builtin_amdgcn_rcpf(e0 + 1.0f);
        float e1 = __expf(2.0f * a1[j]);
        m1[j] = 1.0f - 2.0f * __builtin_amdgcn_rcpf(e1 + 1.0f);
    }

    // ---- pair exchange via shfl_xor(1) ----
    float tA[8], tB[8];
    #pragma unroll
    for (int j = 0; j < 4; ++j) {
        float o0 = __shfl_xor(m0[j], 1, 64);
        float o1 = __shfl_xor(m1[j], 1, 64);
        tA[j]     = h ? o0 : m0[j];
        tA[j + 4] = h ? m0[j] : o0;
        tB[j]     = h ? o1 : m1[j];
        tB[j + 4] = h ? m1[j] : o1;
    }

    // ---- matvec: lane computes outputs [h*8, h*8+8); 2x ds_read_b128 per row
    //      (both addresses wave-uniform per parity class -> pure broadcast) ----
    const int base = h * 8;
    const float4v* wrow = (const float4v*)&sW[base][0];
    float accA[8], accB[8];
    #pragma unroll
    for (int j = 0; j < 8; ++j) {
        float4v w0 = wrow[2 * j];
        float4v w1 = wrow[2 * j + 1];
        float bj = sB[base + j];
        accA[j] = bj + w0.x * tA[0] + w0.y * tA[1] + w0.z * tA[2] + w0.w * tA[3]
                     + w1.x * tA[4] + w1.y * tA[5] + w1.z * tA[6] + w1.w * tA[7];
        accB[j] = bj + w0.x * tB[0] + w0.y * tB[1] + w0.z * tB[2] + w0.w * tB[3]
                     + w1.x * tB[4] + w1.y * tB[5] + w1.z * tB[6] + w1.w * tB[7];
    }

    // ---- nontemporal stores: don't evict x's sectors from L2/L3 ----
    if (v0) {
        float4v* p = (float4v*)(out + (size_t)(g0 >> 1) * 16 + base);
        float4v u0 = {accA[0], accA[1], accA[2], accA[3]};
        float4v u1 = {accA[4], accA[5], accA[6], accA[7]};
        __builtin_nontemporal_store(u0, p);
        __builtin_nontemporal_store(u1, p + 1);
    }
    if (v1) {
        float4v* p = (float4v*)(out + (size_t)(g1 >> 1) * 16 + base);
        float4v u0 = {accB[0], accB[1], accB[2], accB[3]};
        float4v u1 = {accB[4], accB[5], accB[6], accB[7]};
        __builtin_nontemporal_store(u0, p);
        __builtin_nontemporal_store(u1, p + 1);
    }
}

extern "C" void kernel_launch(void* const* d_in, const int* in_sizes, int n_in,
                              void* d_out, int out_size, void* d_ws, size_t ws_size,
                              hipStream_t stream) {
    const float* x   = (const float*)d_in[0];
    const float* rot = (const float*)d_in[1];
    const float* ent = (const float*)d_in[2];
    const float* pw  = (const float*)d_in[3];
    const float* pb  = (const float*)d_in[4];
    float* out = (float*)d_out;

    const int n_rows = in_sizes[0] / 64;            // B*S = 524288
    const int nhalf = n_rows * 2;
    const int block = 256;
    const int grid = (nhalf + block * 2 - 1) / (block * 2);  // 2048
    hipLaunchKernelGGL(qcl_fused, dim3(grid), dim3(block), 0, stream,
                       x, rot, ent, pw, pb, out, n_rows);
}